// Round 10
// baseline (2989.826 us; speedup 1.0000x reference)
//
#include <hip/hip_runtime.h>

// Problem constants (fixed by the reference file).
static constexpr int B  = 16;
static constexpr int N  = 250000;   // 15625 * 16
static constexpr int F  = 500000;
static constexpr int C3 = 3 * F;    // corners = 1,500,000
static constexpr int RW = 48;       // ushorts per vt row: 3 comps * 16 batches (96 B)
static constexpr int AW = 48;       // floats per acc row: 16 batches * 3 comps (192 B)

// ---- workspace layout (bytes): vt | acc | deg  (acc+deg contiguous for one memset) ----
static constexpr size_t W_VT  = 0;                               // 24,000,000
static constexpr size_t W_ACC = (size_t)N * RW * 2;              // 24,000,000
static constexpr size_t W_DEG = W_ACC + (size_t)N * AW * 4;      // 72,000,000
static constexpr size_t W_NEED = W_DEG + (size_t)N * 4;          // 73,000,000 (< proven 89 MB)

__device__ __forceinline__ unsigned short f2bf(float f) {
    unsigned u = __float_as_uint(f);
    return (unsigned short)((u + 0x7FFFu + ((u >> 16) & 1u)) >> 16);  // RNE
}

// Fused: (B,N,3) fp32 -> (N,3,16) bf16 transpose + degree count.
// The deg atomic is FIRE-AND-FORGET (no return use) — the cheap atomic class.
__global__ __launch_bounds__(256) void uls_setup(
    const float* __restrict__ vert, const int* __restrict__ faces,
    unsigned short* __restrict__ vt, unsigned* __restrict__ deg)
{
    __shared__ unsigned short lus[16 * RW];
    int t = threadIdx.x;
    int n0 = blockIdx.x * 16;
    int b = t >> 4, v = t & 15;

    int e = blockIdx.x * 256 + t;          // 4M threads cover C3 = 1.5M corners
    if (e < C3) atomicAdd(&deg[faces[e]], 2u);   // no-return -> global_atomic_add

    const float* s = vert + (size_t)b * (N * 3) + (size_t)(n0 + v) * 3;  // coalesced
    lus[v * RW + 0 * 16 + b] = f2bf(s[0]);
    lus[v * RW + 1 * 16 + b] = f2bf(s[1]);
    lus[v * RW + 2 * 16 + b] = f2bf(s[2]);
    __syncthreads();
    const uint2* lu2 = (const uint2*)lus;
    uint2* d2 = (uint2*)(vt + (size_t)n0 * RW);
    if (t < 192) d2[t] = lu2[t];           // coalesced 1536 B per tile
}

// Face-parallel accumulate: 4 lanes per face, lane q owns batches 4q..4q+3.
// Reads 3 vt rows (3x 8 B per row per lane, coalesced 32 B segments), then
// 36 fire-and-forget fp32 atomics per lane in 48 B contiguous chunks
// (4 lanes cover the full 192 B acc row). No with-return atomics anywhere.
__global__ __launch_bounds__(256) void uls_accum(
    const unsigned short* __restrict__ vt, const int* __restrict__ faces,
    float* __restrict__ acc)
{
    int idx = blockIdx.x * 256 + threadIdx.x;
    if (idx >= F * 4) return;
    int f = idx >> 2;                       // wave = 16 faces x 4 lanes
    int q = idx & 3;

    int a = faces[3 * f + 0];               // 4 lanes of a face share -> L1 broadcast
    int b = faces[3 * f + 1];
    int c = faces[3 * f + 2];

    const unsigned short* ra = vt + (size_t)a * RW + 4 * q;
    const unsigned short* rb = vt + (size_t)b * RW + 4 * q;
    const unsigned short* rc = vt + (size_t)c * RW + 4 * q;

    // 9 independent 8 B loads in flight
    uint2 ua0 = *(const uint2*)(ra +  0), ua1 = *(const uint2*)(ra + 16), ua2 = *(const uint2*)(ra + 32);
    uint2 ub0 = *(const uint2*)(rb +  0), ub1 = *(const uint2*)(rb + 16), ub2 = *(const uint2*)(rb + 32);
    uint2 uc0 = *(const uint2*)(rc +  0), uc1 = *(const uint2*)(rc + 16), uc2 = *(const uint2*)(rc + 32);

    float va[3][4], vb[3][4], vc[3][4];
    auto unpack = [](uint2 u, float (&d)[4]) {
        d[0] = __uint_as_float(u.x << 16);
        d[1] = __uint_as_float(u.x & 0xFFFF0000u);
        d[2] = __uint_as_float(u.y << 16);
        d[3] = __uint_as_float(u.y & 0xFFFF0000u);
    };
    unpack(ua0, va[0]); unpack(ua1, va[1]); unpack(ua2, va[2]);
    unpack(ub0, vb[0]); unpack(ub1, vb[1]); unpack(ub2, vb[2]);
    unpack(uc0, vc[0]); unpack(uc1, vc[1]); unpack(uc2, vc[2]);

    // acc row layout (N,16,3): lane q covers batches 4q..4q+3 = 48 B contiguous
    float* pa = acc + (size_t)a * AW + q * 12;
    float* pb = acc + (size_t)b * AW + q * 12;
    float* pc = acc + (size_t)c * AW + q * 12;

#pragma unroll
    for (int k = 0; k < 4; ++k) {           // batch within quarter
#pragma unroll
        for (int cc = 0; cc < 3; ++cc) {    // component
            int o = k * 3 + cc;
            unsafeAtomicAdd(pa + o, vb[cc][k] + vc[cc][k]);
            unsafeAtomicAdd(pb + o, va[cc][k] + vc[cc][k]);
            unsafeAtomicAdd(pc + o, va[cc][k] + vb[cc][k]);
        }
    }
}

// Finalize: 4 lanes per vertex; acc reads fully coalesced (192 B/vertex),
// output transposed through LDS for coalesced (B,N) writes.
__global__ __launch_bounds__(256) void uls_finalize(
    const unsigned short* __restrict__ vt, const float* __restrict__ acc,
    const unsigned* __restrict__ deg, float* __restrict__ out)
{
    __shared__ float lds[16 * 65];
    int t = threadIdx.x;
    int q = t & 3;
    int v = t >> 2;
    int n = blockIdx.x * 64 + v;
    bool n_ok = (n < N);

    if (n_ok) {
        const float* ar = acc + (size_t)n * AW + q * 12;   // 48 B, 16-B aligned
        float4 s0 = *(const float4*)(ar + 0);
        float4 s1 = *(const float4*)(ar + 4);
        float4 s2 = *(const float4*)(ar + 8);
        float sums[12] = { s0.x, s0.y, s0.z, s0.w, s1.x, s1.y, s1.z, s1.w,
                           s2.x, s2.y, s2.z, s2.w };

        const unsigned short* rs = vt + (size_t)n * RW + 4 * q;
        float self[3][4];
        auto unpack = [](uint2 u, float (&d)[4]) {
            d[0] = __uint_as_float(u.x << 16);
            d[1] = __uint_as_float(u.x & 0xFFFF0000u);
            d[2] = __uint_as_float(u.y << 16);
            d[3] = __uint_as_float(u.y & 0xFFFF0000u);
        };
        unpack(*(const uint2*)(rs +  0), self[0]);
        unpack(*(const uint2*)(rs + 16), self[1]);
        unpack(*(const uint2*)(rs + 32), self[2]);

        float d = (float)deg[n];
        float inv = 1.0f / fmaxf(d, 1.0f);
#pragma unroll
        for (int k = 0; k < 4; ++k) {
            float lx = sums[k * 3 + 0] * inv - self[0][k];
            float ly = sums[k * 3 + 1] * inv - self[1][k];
            float lz = sums[k * 3 + 2] * inv - self[2][k];
            lds[(4 * q + k) * 65 + v] = sqrtf(lx * lx + ly * ly + lz * lz);
        }
    }
    __syncthreads();
    int vo = t & 63;
    int nn = blockIdx.x * 64 + vo;
    if (nn < N) {
#pragma unroll
        for (int k = 0; k < 4; ++k) {
            int bo = (t >> 6) + 4 * k;
            out[(size_t)bo * N + nn] = lds[bo * 65 + vo];   // coalesced
        }
    }
}

extern "C" void kernel_launch(void* const* d_in, const int* in_sizes, int n_in,
                              void* d_out, int out_size, void* d_ws, size_t ws_size,
                              hipStream_t stream) {
    const float* vert  = (const float*)d_in[0];   // (B, N, 3) fp32
    const int*   faces = (const int*)d_in[1];     // (F, 3) int32
    float* out = (float*)d_out;                   // (B, N) fp32
    char* ws = (char*)d_ws;
    (void)ws_size;  // W_NEED = 73 MB; 89 MB proven available in R7

    unsigned short* vt  = (unsigned short*)(ws + W_VT);
    float*          acc = (float*)(ws + W_ACC);
    unsigned*       deg = (unsigned*)(ws + W_DEG);

    // zero acc + deg in one contiguous 49 MB memset
    hipMemsetAsync(ws + W_ACC, 0, (W_NEED - W_ACC), stream);

    uls_setup<<<N / 16, 256, 0, stream>>>(vert, faces, vt, deg);
    uls_accum<<<(F * 4 + 255) / 256, 256, 0, stream>>>(vt, faces, acc);
    uls_finalize<<<(N + 63) / 64, 256, 0, stream>>>(vt, acc, deg, out);
}